// Round 4
// baseline (1978.163 us; speedup 1.0000x reference)
//
#include <hip/hip_runtime.h>
#include <cmath>

#define B_ 256
#define T_ 20
#define H_ 512
#define V_ 8964
#define LQ_ 40
#define LH_ 80
#define LI_ 49
#define BT_ (B_ * T_)   // 5120
#define BH_ (B_ * H_)   // 131072
#define NPAD_ 9088      // V_ padded to multiple of 128
#define BETA_ 3.0f

typedef __attribute__((ext_vector_type(8))) short bf16x8;
typedef __attribute__((ext_vector_type(4))) float f32x4;
typedef __attribute__((ext_vector_type(8))) unsigned short u16x8;

static __device__ __forceinline__ unsigned short f2bf(float f) {
    union { float f; unsigned u; } v; v.f = f;
    unsigned r = v.u + 0x7FFF + ((v.u >> 16) & 1);
    return (unsigned short)(r >> 16);
}
static __device__ __forceinline__ float bf2f(unsigned short u) {
    union { unsigned u; float f; } v; v.u = ((unsigned)u) << 16;
    return v.f;
}

// ---------------------------------------------------------------------------
// f32 -> bf16 convert with optional row padding (rows >= srcRows get zeros).
// ---------------------------------------------------------------------------
__global__ __launch_bounds__(256) void cvt_kernel(
    const float* __restrict__ src, unsigned short* __restrict__ dst,
    long long srcRows, long long cols, long long dstRows)
{
    const long long total = dstRows * cols;
    const long long e0 = ((long long)blockIdx.x * 256 + threadIdx.x) * 8;
    if (e0 >= total) return;
    const long long row = e0 / cols;
    u16x8 v;
    if (row < srcRows) {
        float4 a = *reinterpret_cast<const float4*>(src + e0);
        float4 b = *reinterpret_cast<const float4*>(src + e0 + 4);
        v[0] = f2bf(a.x); v[1] = f2bf(a.y); v[2] = f2bf(a.z); v[3] = f2bf(a.w);
        v[4] = f2bf(b.x); v[5] = f2bf(b.y); v[6] = f2bf(b.z); v[7] = f2bf(b.w);
    } else {
        v = (u16x8)0;
    }
    *reinterpret_cast<u16x8*>(dst + e0) = v;
}

static void cvt(hipStream_t s, const float* src, unsigned short* dst,
                long long srcRows, long long cols, long long dstRows)
{
    long long total = dstRows * cols;
    cvt_kernel<<<dim3((unsigned)((total / 8 + 255) / 256)), dim3(256), 0, s>>>(
        src, dst, srcRows, cols, dstRows);
}

// ---------------------------------------------------------------------------
// Gate-permuting convert for LSTM weights [2048][512] -> bf16:
// dst row n' = (h>>4)*64 + g*16 + (h&15)  <-  src row g*512+h.
// (All 4 gates of an h land in one lane's j-fragments after MFMA.)
// ---------------------------------------------------------------------------
__global__ __launch_bounds__(256) void cvt_perm_kernel(
    const float* __restrict__ src, unsigned short* __restrict__ dst)
{
    const long long e0 = ((long long)blockIdx.x * 256 + threadIdx.x) * 8;
    if (e0 >= 2048LL * 512) return;
    const int drow = (int)(e0 >> 9);
    const int col = (int)(e0 & 511);
    const int g = (drow >> 4) & 3;
    const int hsrc = ((drow >> 6) << 4) | (drow & 15);
    const int srow = (g << 9) | hsrc;
    const float* sp = src + (long long)srow * 512 + col;
    float4 a = *reinterpret_cast<const float4*>(sp);
    float4 b = *reinterpret_cast<const float4*>(sp + 4);
    u16x8 v;
    v[0] = f2bf(a.x); v[1] = f2bf(a.y); v[2] = f2bf(a.z); v[3] = f2bf(a.w);
    v[4] = f2bf(b.x); v[5] = f2bf(b.y); v[6] = f2bf(b.z); v[7] = f2bf(b.w);
    *reinterpret_cast<u16x8*>(dst + e0) = v;
}

// dst[n'] = b1[orig(n')] + b2[orig(n')], n' in [0,2048)
__global__ __launch_bounds__(256) void bias_perm_kernel(
    const float* __restrict__ b1, const float* __restrict__ b2,
    float* __restrict__ dst)
{
    const int n = blockIdx.x * 256 + threadIdx.x;
    if (n < 2048) {
        const int g = (n >> 4) & 3;
        const int h = ((n >> 6) << 4) | (n & 15);
        const int orig = (g << 9) | h;
        dst[n] = b1[orig] + b2[orig];
    }
}

// ---------------------------------------------------------------------------
// A-fragment loader: 8 contiguous elements at element-index idx.
// AF32=0: bf16 source (int4). AF32=1: fp32 source, converted to bf16.
// ---------------------------------------------------------------------------
template <int AF32>
static __device__ __forceinline__ int4 ldA8(const void* A, long long idx)
{
    if constexpr (AF32) {
        const float* p = (const float*)A + idx;
        float4 a = *reinterpret_cast<const float4*>(p);
        float4 b = *reinterpret_cast<const float4*>(p + 4);
        union { int4 i4; unsigned short u[8]; } r;
        r.u[0] = f2bf(a.x); r.u[1] = f2bf(a.y); r.u[2] = f2bf(a.z); r.u[3] = f2bf(a.w);
        r.u[4] = f2bf(b.x); r.u[5] = f2bf(b.y); r.u[6] = f2bf(b.z); r.u[7] = f2bf(b.w);
        return r.i4;
    } else {
        return *reinterpret_cast<const int4*>((const unsigned short*)A + idx);
    }
}

// ---------------------------------------------------------------------------
// bf16 MFMA GEMM: C[m,n] = act(A[m,:]·W[n,:] + bias1[n] + bias2[n])
// 128x128 tile, BK=32, 4 waves. Bijective XCD swizzle + m-fastest tile order
// (each XCD owns an N-band of W and streams all M through it -> W L2-hot).
// ---------------------------------------------------------------------------
template <int ACT, int OUTBF, int AF32>
__global__ __launch_bounds__(256, 2) void mfma_gemm(
    const void* __restrict__ A, const unsigned short* __restrict__ W,
    const float* __restrict__ bias1, const float* __restrict__ bias2,
    void* __restrict__ C, long long ldc, int Nreal, int K)
{
    __shared__ __align__(16) unsigned short As[128][32];
    __shared__ __align__(16) unsigned short Bs[128][32];
    const int tid = threadIdx.x;
    const int lane = tid & 63;
    const int wave = tid >> 6;
    const int wm = wave >> 1, wn = wave & 1;

    // XCD-aware bijective swizzle (m204), then m-fastest decomposition.
    const int nwg = gridDim.x * gridDim.y;
    const int orig = blockIdx.y * gridDim.x + blockIdx.x;
    const int xcd = orig & 7, base = orig >> 3;
    const int q8 = nwg >> 3, r8 = nwg & 7;
    const int wg = (xcd < r8 ? xcd * (q8 + 1) : r8 * (q8 + 1) + (xcd - r8) * q8) + base;
    const int m0 = (wg % gridDim.y) * 128;
    const int n0 = (wg / gridDim.y) * 128;

    const int r = tid >> 2;
    const int ck = (tid & 3) * 8;

    const unsigned short* Wp = W + (long long)n0 * K;

    f32x4 acc[4][4] = {};

    int4 ra0, ra1, rb0, rb1;
    ra0 = ldA8<AF32>(A, (long long)(m0 + r) * K + ck);
    ra1 = ldA8<AF32>(A, (long long)(m0 + r + 64) * K + ck);
    rb0 = *reinterpret_cast<const int4*>(Wp + (long long)r * K + ck);
    rb1 = *reinterpret_cast<const int4*>(Wp + (long long)(r + 64) * K + ck);

    for (int k0 = 0; k0 < K; k0 += 32) {
        __syncthreads();
        *reinterpret_cast<int4*>(&As[r][ck]) = ra0;
        *reinterpret_cast<int4*>(&As[r + 64][ck]) = ra1;
        *reinterpret_cast<int4*>(&Bs[r][ck]) = rb0;
        *reinterpret_cast<int4*>(&Bs[r + 64][ck]) = rb1;
        __syncthreads();
        if (k0 + 32 < K) {
            const int kn = k0 + 32 + ck;
            ra0 = ldA8<AF32>(A, (long long)(m0 + r) * K + kn);
            ra1 = ldA8<AF32>(A, (long long)(m0 + r + 64) * K + kn);
            rb0 = *reinterpret_cast<const int4*>(Wp + (long long)r * K + kn);
            rb1 = *reinterpret_cast<const int4*>(Wp + (long long)(r + 64) * K + kn);
        }
        const int lr = lane & 15, lk = (lane >> 4) * 8;
        bf16x8 af[4], bfr[4];
#pragma unroll
        for (int i = 0; i < 4; ++i) {
            af[i]  = *reinterpret_cast<const bf16x8*>(&As[wm * 64 + i * 16 + lr][lk]);
            bfr[i] = *reinterpret_cast<const bf16x8*>(&Bs[wn * 64 + i * 16 + lr][lk]);
        }
#pragma unroll
        for (int i = 0; i < 4; ++i)
#pragma unroll
            for (int j = 0; j < 4; ++j)
                acc[i][j] = __builtin_amdgcn_mfma_f32_16x16x32_bf16(
                    af[i], bfr[j], acc[i][j], 0, 0, 0);
    }

    // D mapping: col=lane&15, row=(lane>>4)*4+reg  [measured m89/m91]
    const int lr = lane & 15, lrow4 = (lane >> 4) * 4;
#pragma unroll
    for (int j = 0; j < 4; ++j) {
        const int col = n0 + wn * 64 + j * 16 + lr;
        if (col >= Nreal) continue;
        float bsum = 0.f;
        if (bias1) bsum += bias1[col];
        if (bias2) bsum += bias2[col];
#pragma unroll
        for (int i = 0; i < 4; ++i) {
#pragma unroll
            for (int rr = 0; rr < 4; ++rr) {
                const int row = m0 + wm * 64 + i * 16 + lrow4 + rr;
                float v = acc[i][j][rr] + bsum;
                if (ACT == 1) v = tanhf(v);
                if (ACT == 2) v = fmaxf(v, 0.f);
                if (OUTBF)
                    ((unsigned short*)C)[(long long)row * ldc + col] = f2bf(v);
                else
                    ((float*)C)[(long long)row * ldc + col] = v;
            }
        }
    }
}

static void mgemm(hipStream_t s, int act, int outbf, int af32,
                  const void* A, const unsigned short* W,
                  const float* b1, const float* b2,
                  void* C, long long ldc, int M, int Nreal, int K)
{
    dim3 grid((Nreal + 127) / 128, M / 128), blk(256);
#define MG(a, o, f) mfma_gemm<a, o, f><<<grid, blk, 0, s>>>(A, W, b1, b2, C, ldc, Nreal, K)
    if (af32) {
        if (outbf) { if (act == 1) MG(1,1,1); else if (act == 2) MG(2,1,1); else MG(0,1,1); }
        else       { if (act == 1) MG(1,0,1); else if (act == 2) MG(2,0,1); else MG(0,0,1); }
    } else {
        if (outbf) { if (act == 1) MG(1,1,0); else if (act == 2) MG(2,1,0); else MG(0,1,0); }
        else       { if (act == 1) MG(1,0,0); else if (act == 2) MG(2,0,0); else MG(0,0,0); }
    }
#undef MG
}

// ---------------------------------------------------------------------------
// Persistent fused LSTM. ONE launch, 64 blocks x 256 threads (all co-resident:
// 64 <= 256 CUs), 21 pipelined intervals separated by a device-scope atomic
// grid barrier. Blocks 0..31: layer 0 step s; blocks 32..63: layer 1 step s-1.
// Gate-permuted weights (n' = (h>>4)*64 + g*16 + (h&15)) put the 4 gates of h
// into one lane's j-fragments -> cell computed fully in registers.
// c is block-owned fp32; h is bf16 double-buffered and crosses blocks only
// through the barrier (release-add + acquire-spin + threadfence).
// ---------------------------------------------------------------------------
__global__ __launch_bounds__(256, 1) void lstm_persistent_kernel(
    const unsigned short* __restrict__ emb_bf,    // [b*T+t][512]
    const unsigned short* __restrict__ Wih0p, const unsigned short* __restrict__ Whh0p,
    const unsigned short* __restrict__ Wih1p, const unsigned short* __restrict__ Whh1p,
    const float* __restrict__ bp0, const float* __restrict__ bp1,
    unsigned short* __restrict__ hbuf,            // [4][B][512] bf16
    float* __restrict__ st_h,                     // [2][B][512]
    float* __restrict__ st_c,                     // [2][B][512]
    unsigned short* __restrict__ h_top,           // [b*T+t][512] bf16
    int* bar)
{
    __shared__ __align__(16) unsigned short As[128][32];
    __shared__ __align__(16) unsigned short Bs[128][32];

    const int gid = blockIdx.x;
    const int grp = gid >> 5;
    const int id = gid & 31;
    const int tid = threadIdx.x;
    const int lane = tid & 63;
    const int wave = tid >> 6;
    const int wm = wave >> 1, wn = wave & 1;
    const int m0 = (id >> 4) * 128, n0 = (id & 15) * 128;
    const int r = tid >> 2, ck = (tid & 3) * 8;

    const unsigned short* W1 = (grp ? Wih1p : Wih0p) + (long long)n0 * H_;
    const unsigned short* W2 = (grp ? Whh1p : Whh0p) + (long long)n0 * H_;
    float* c = st_c + (long long)grp * BH_;

    // per-lane epilogue constants
    const int lr = lane & 15;
    const int hi4 = (lane >> 4) * 4;
    const int group = (n0 >> 6) + wn;
    const int h = (group << 4) + lr;
    const float* bp = grp ? bp1 : bp0;
    float bg[4];
#pragma unroll
    for (int g = 0; g < 4; ++g) bg[g] = bp[group * 64 + g * 16 + lr];

    for (int s = 0; s <= T_; ++s) {
        const bool active = (grp == 0) ? (s < T_) : (s >= 1);
        if (active) {
            const int t = (grp == 0) ? s : s - 1;
            const int pr = s & 1;
            const unsigned short *A1, *A2;
            long long sA1, sA2;
            unsigned short* hout;
            if (grp == 0) {
                A1 = emb_bf + ((long long)m0 * T_ + t) * H_; sA1 = (long long)T_ * H_;
                A2 = hbuf + (long long)pr * BH_ + (long long)m0 * H_; sA2 = H_;
                hout = hbuf + (long long)(pr ^ 1) * BH_;
            } else {
                A1 = hbuf + (long long)pr * BH_ + (long long)m0 * H_; sA1 = H_;
                A2 = hbuf + (long long)(2 + pr) * BH_ + (long long)m0 * H_; sA2 = H_;
                hout = hbuf + (long long)(2 + (pr ^ 1)) * BH_;
            }

            f32x4 acc[4][4] = {};
            int4 ra0, ra1, rb0, rb1;
            ra0 = *reinterpret_cast<const int4*>(A1 + (long long)r * sA1 + ck);
            ra1 = *reinterpret_cast<const int4*>(A1 + (long long)(r + 64) * sA1 + ck);
            rb0 = *reinterpret_cast<const int4*>(W1 + (long long)r * H_ + ck);
            rb1 = *reinterpret_cast<const int4*>(W1 + (long long)(r + 64) * H_ + ck);

            for (int kk = 0; kk < 32; ++kk) {
                __syncthreads();
                *reinterpret_cast<int4*>(&As[r][ck]) = ra0;
                *reinterpret_cast<int4*>(&As[r + 64][ck]) = ra1;
                *reinterpret_cast<int4*>(&Bs[r][ck]) = rb0;
                *reinterpret_cast<int4*>(&Bs[r + 64][ck]) = rb1;
                __syncthreads();
                if (kk + 1 < 32) {
                    const int p = (kk + 1) >> 4;
                    const int k0 = ((kk + 1) & 15) * 32;
                    const unsigned short* An = p ? A2 : A1;
                    const long long sA = p ? sA2 : sA1;
                    const unsigned short* Wn = p ? W2 : W1;
                    ra0 = *reinterpret_cast<const int4*>(An + (long long)r * sA + k0 + ck);
                    ra1 = *reinterpret_cast<const int4*>(An + (long long)(r + 64) * sA + k0 + ck);
                    rb0 = *reinterpret_cast<const int4*>(Wn + (long long)r * H_ + k0 + ck);
                    rb1 = *reinterpret_cast<const int4*>(Wn + (long long)(r + 64) * H_ + k0 + ck);
                }
                const int lk = (lane >> 4) * 8;
                bf16x8 af[4], bfr[4];
#pragma unroll
                for (int i = 0; i < 4; ++i) {
                    af[i]  = *reinterpret_cast<const bf16x8*>(&As[wm * 64 + i * 16 + lr][lk]);
                    bfr[i] = *reinterpret_cast<const bf16x8*>(&Bs[wn * 64 + i * 16 + lr][lk]);
                }
#pragma unroll
                for (int i = 0; i < 4; ++i)
#pragma unroll
                    for (int j = 0; j < 4; ++j)
                        acc[i][j] = __builtin_amdgcn_mfma_f32_16x16x32_bf16(
                            af[i], bfr[j], acc[i][j], 0, 0, 0);
            }

            // register cell (gates i,f,g,o in j = 0..3)
#pragma unroll
            for (int i = 0; i < 4; ++i) {
#pragma unroll
                for (int rr = 0; rr < 4; ++rr) {
                    const int b = m0 + wm * 64 + i * 16 + hi4 + rr;
                    const float gi = acc[i][0][rr] + bg[0];
                    const float gf = acc[i][1][rr] + bg[1];
                    const float gg = acc[i][2][rr] + bg[2];
                    const float go = acc[i][3][rr] + bg[3];
                    const long long cidx = (long long)b * H_ + h;
                    const float i_ = 1.f / (1.f + expf(-gi));
                    const float f_ = 1.f / (1.f + expf(-gf));
                    const float o_ = 1.f / (1.f + expf(-go));
                    const float cn = f_ * c[cidx] + i_ * tanhf(gg);
                    const float hn = o_ * tanhf(cn);
                    c[cidx] = cn;
                    hout[cidx] = f2bf(hn);
                    if (grp == 1) h_top[((long long)b * T_ + t) * H_ + h] = f2bf(hn);
                    if (t == T_ - 1) st_h[(long long)grp * BH_ + cidx] = hn;
                }
            }
        }
        if (s < T_) {
            __syncthreads();
            if (tid == 0) {
                __hip_atomic_fetch_add(bar, 1, __ATOMIC_RELEASE, __HIP_MEMORY_SCOPE_AGENT);
                const int tgt = 64 * (s + 1);
                while (__hip_atomic_load(bar, __ATOMIC_ACQUIRE, __HIP_MEMORY_SCOPE_AGENT) < tgt)
                    __builtin_amdgcn_s_sleep(1);
                __threadfence();
            }
            __syncthreads();
        }
    }
}

// ---------------------------------------------------------------------------
// Fused attention over bf16 ctx: logits -> softmax -> weighted sum (bf16 out).
// ---------------------------------------------------------------------------
__global__ __launch_bounds__(256) void attend_kernel(
    const unsigned short* __restrict__ ctx, int Lx,
    const float* __restrict__ proj,
    const float* __restrict__ wa, const float* __restrict__ ba,
    unsigned short* __restrict__ fcat, int off)
{
    __shared__ float p_lds[512];
    __shared__ float wa_lds[512];
    __shared__ float lg[96];
    const int bt = blockIdx.x;
    const int b = bt / T_;
    const int tid = threadIdx.x;

    p_lds[tid] = proj[(long long)bt * H_ + tid];
    p_lds[tid + 256] = proj[(long long)bt * H_ + tid + 256];
    wa_lds[tid] = wa[tid];
    wa_lds[tid + 256] = wa[tid + 256];
    __syncthreads();

    const int wid = tid >> 6, lane = tid & 63;
    const float bav = ba[0];
    for (int l = wid; l < Lx; l += 4) {
        const unsigned short* crow = ctx + ((long long)b * Lx + l) * H_;
        float acc = 0.f;
#pragma unroll
        for (int j = 0; j < 8; ++j) {
            const int hp = lane + 64 * j;
            acc += wa_lds[hp] * tanhf(bf2f(crow[hp]) + p_lds[hp]);
        }
        for (int o = 32; o > 0; o >>= 1) acc += __shfl_down(acc, o);
        if (lane == 0) lg[l] = acc + bav;
    }
    __syncthreads();
    if (tid == 0) {
        float m = -1e30f;
        for (int l = 0; l < Lx; ++l) m = fmaxf(m, lg[l]);
        float ssum = 0.f;
        for (int l = 0; l < Lx; ++l) { const float e = expf(lg[l] - m); lg[l] = e; ssum += e; }
        const float inv = 1.f / ssum;
        for (int l = 0; l < Lx; ++l) lg[l] *= inv;
    }
    __syncthreads();
    for (int hp = tid; hp < H_; hp += 256) {
        float acc = 0.f;
        for (int l = 0; l < Lx; ++l)
            acc += lg[l] * bf2f(ctx[((long long)b * Lx + l) * H_ + hp]);
        fcat[(long long)bt * (3 * H_) + off + hp] = f2bf(acc);
    }
}

// fusion_bf[:, 0:512] = h_top_bf
__global__ __launch_bounds__(256) void copy_fusion_left(
    const unsigned short* __restrict__ h_top, unsigned short* __restrict__ fusion)
{
    const long long e0 = ((long long)blockIdx.x * 256 + threadIdx.x) * 8;  // < BT*H
    const long long rr = e0 >> 9, cpos = e0 & 511;
    *reinterpret_cast<u16x8*>(&fusion[rr * 1024 + cpos]) =
        *reinterpret_cast<const u16x8*>(&h_top[e0]);
}

// In-place log_softmax(BETA * x) per row of V_; online (max,sum) single pass.
__global__ __launch_bounds__(256) void log_softmax_kernel(float* __restrict__ out)
{
    __shared__ float red_m[4], red_s[4];
    __shared__ float bc;
    const long long base = (long long)blockIdx.x * V_;
    const int tid = threadIdx.x, lane = tid & 63, wid = tid >> 6;

    float m = -1e30f, s = 0.f;
    for (int v = tid; v < V_; v += 256) {
        const float x = BETA_ * out[base + v];
        const float nm = fmaxf(m, x);
        s = s * expf(m - nm) + expf(x - nm);
        m = nm;
    }
    for (int o = 32; o > 0; o >>= 1) {
        const float mo = __shfl_down(m, o), so = __shfl_down(s, o);
        const float nm = fmaxf(m, mo);
        s = s * expf(m - nm) + so * expf(mo - nm);
        m = nm;
    }
    if (lane == 0) { red_m[wid] = m; red_s[wid] = s; }
    __syncthreads();
    if (tid == 0) {
        float mm = red_m[0], ss = red_s[0];
        for (int i = 1; i < 4; ++i) {
            const float nm = fmaxf(mm, red_m[i]);
            ss = ss * expf(mm - nm) + red_s[i] * expf(red_m[i] - nm);
            mm = nm;
        }
        bc = mm + logf(ss);
    }
    __syncthreads();
    const float ls = bc;
    for (int v = tid; v < V_; v += 256)
        out[base + v] = BETA_ * out[base + v] - ls;
}

// ---------------------------------------------------------------------------
extern "C" void kernel_launch(void* const* d_in, const int* in_sizes, int n_in,
                              void* d_out_, int out_size, void* d_ws, size_t ws_size,
                              hipStream_t stream)
{
    const float* emb      = (const float*)d_in[0];
    const float* question = (const float*)d_in[1];
    const float* history  = (const float*)d_in[2];
    const float* image    = (const float*)d_in[3];
    const float* h0       = (const float*)d_in[4];
    const float* c0       = (const float*)d_in[5];
    const float* Wih      = (const float*)d_in[6];
    const float* Whh      = (const float*)d_in[7];
    const float* bih      = (const float*)d_in[8];
    const float* bhh      = (const float*)d_in[9];
    const float* Wq    = (const float*)d_in[10]; const float* bq    = (const float*)d_in[11];
    const float* Wansq = (const float*)d_in[12]; const float* bansq = (const float*)d_in[13];
    const float* waq   = (const float*)d_in[14]; const float* baq   = (const float*)d_in[15];
    const float* Wh    = (const float*)d_in[16]; const float* bh    = (const float*)d_in[17];
    const float* Wansh = (const float*)d_in[18]; const float* bansh = (const float*)d_in[19];
    const float* wah   = (const float*)d_in[20]; const float* bah   = (const float*)d_in[21];
    const float* Wi    = (const float*)d_in[22]; const float* bi    = (const float*)d_in[23];
    const float* Wansi = (const float*)d_in[24]; const float* bansi = (const float*)d_in[25];
    const float* wai   = (const float*)d_in[26]; const float* bai   = (const float*)d_in[27];
    const float* Wcat  = (const float*)d_in[28]; const float* bcat  = (const float*)d_in[29];
    const float* Wd1   = (const float*)d_in[30]; const float* bd1   = (const float*)d_in[31];
    const float* Wd2   = (const float*)d_in[32]; const float* bd2   = (const float*)d_in[33];

    float* out = (float*)d_out_;

    // ---- workspace layout ----
    int*   bar  = (int*)d_ws;                          // barrier counter (256 B pad)
    float* st_h = (float*)((char*)d_ws + 256);         // 2*BH fp32 (st_c follows: tail copy)
    float* st_c = st_h + 2LL * BH_;                    // 2*BH fp32
    float* bp0  = st_c + 2LL * BH_;                    // 2048
    float* bp1  = bp0 + 2048;                          // 2048
    unsigned short* hbuf   = (unsigned short*)(bp1 + 2048);     // 4*BH bf16
    unsigned short* Wih0p  = hbuf + 4LL * BH_;                  // 2048*512 each
    unsigned short* Whh0p  = Wih0p + 2048LL * H_;
    unsigned short* Wih1p  = Whh0p + 2048LL * H_;
    unsigned short* Whh1p  = Wih1p + 2048LL * H_;
    unsigned short* emb_bf = Whh1p + 2048LL * H_;               // BT*H
    unsigned short* h_top_bf = emb_bf + (long long)BT_ * H_;    // BT*H
    unsigned short* q_emb_bf = h_top_bf + (long long)BT_ * H_;  // B*LQ*H
    unsigned short* h_emb_bf = q_emb_bf + (long long)B_ * LQ_ * H_;
    unsigned short* i_emb_bf = h_emb_bf + (long long)B_ * LH_ * H_;
    unsigned short* dec1_bf  = i_emb_bf + (long long)B_ * LI_ * H_;  // BT*4H
    unsigned short* Wd2p_bf  = dec1_bf + (long long)BT_ * 4 * H_;    // NPAD*4H

    // ---- phase-A scratch inside d_out (dead before phase C) ----
    unsigned short* Wq_bf = (unsigned short*)out;                   // H*2H each
    unsigned short* Wh_bf = Wq_bf + (long long)H_ * 2 * H_;
    unsigned short* Wi_bf = Wh_bf + (long long)H_ * 2 * H_;

    // 1) small weight converts (context projections keep fp32 A via AF32 path)
    cvt(stream, Wq, Wq_bf, 1, (long long)H_ * 2 * H_, 1);
    cvt(stream, Wh, Wh_bf, 1, (long long)H_ * 2 * H_, 1);
    cvt(stream, Wi, Wi_bf, 1, (long long)H_ * 2 * H_, 1);

    // 2) LSTM prep: emb, gate-permuted weights/biases, state init, barrier=0
    cvt(stream, emb, emb_bf, 1, (long long)BT_ * H_, 1);
    cvt_perm_kernel<<<dim3(512), dim3(256), 0, stream>>>(Wih, Wih0p);
    cvt_perm_kernel<<<dim3(512), dim3(256), 0, stream>>>(Whh, Whh0p);
    cvt_perm_kernel<<<dim3(512), dim3(256), 0, stream>>>(Wih + 2048LL * H_, Wih1p);
    cvt_perm_kernel<<<dim3(512), dim3(256), 0, stream>>>(Whh + 2048LL * H_, Whh1p);
    bias_perm_kernel<<<dim3(8), dim3(256), 0, stream>>>(bih, bhh, bp0);
    bias_perm_kernel<<<dim3(8), dim3(256), 0, stream>>>(bih + 2048, bhh + 2048, bp1);
    cvt(stream, h0, hbuf, 1, BH_, 1);                   // layer0 init -> slot 0
    cvt(stream, h0 + BH_, hbuf + 3LL * BH_, 1, BH_, 1); // layer1 init -> slot 3
    hipMemcpyAsync(st_c, c0, 2LL * BH_ * sizeof(float), hipMemcpyDeviceToDevice, stream);
    hipMemsetAsync(bar, 0, 256, stream);

    // 3) context projections (fp32 A converted in-GEMM)
    mgemm(stream, 0, 1, 1, question, Wq_bf, bq, nullptr, q_emb_bf, H_, B_ * LQ_, H_, 2 * H_);
    mgemm(stream, 0, 1, 1, history,  Wh_bf, bh, nullptr, h_emb_bf, H_, B_ * LH_, H_, 2 * H_);
    mgemm(stream, 0, 1, 1, image,    Wi_bf, bi, nullptr, i_emb_bf, H_, B_ * LI_, H_, 2 * H_);

    // 4) persistent fused LSTM (one launch, internal grid barriers)
    lstm_persistent_kernel<<<dim3(64), dim3(256), 0, stream>>>(
        emb_bf, Wih0p, Whh0p, Wih1p, Whh1p, bp0, bp1,
        hbuf, st_h, st_c, h_top_bf, bar);

    // ---- phase-C scratch inside d_out ----
    float* proj = out;                                              // BT*H fp32
    unsigned short* fcat_bf   = (unsigned short*)(proj + (long long)BT_ * H_); // BT*3H
    unsigned short* fusion_bf = fcat_bf + (long long)BT_ * 3 * H_;  // BT*2H
    unsigned short* Wansq_bf  = fusion_bf + (long long)BT_ * 2 * H_;
    unsigned short* Wansh_bf  = Wansq_bf + (long long)H_ * H_;
    unsigned short* Wansi_bf  = Wansh_bf + (long long)H_ * H_;
    unsigned short* Wcat_bf   = Wansi_bf + (long long)H_ * H_;      // H*3H
    unsigned short* Wd1_bf    = Wcat_bf + (long long)H_ * 3 * H_;   // 4H*2H

    // 5) phase-C converts
    cvt(stream, Wansq, Wansq_bf, 1, (long long)H_ * H_, 1);
    cvt(stream, Wansh, Wansh_bf, 1, (long long)H_ * H_, 1);
    cvt(stream, Wansi, Wansi_bf, 1, (long long)H_ * H_, 1);
    cvt(stream, Wcat, Wcat_bf, 1, (long long)H_ * 3 * H_, 1);
    cvt(stream, Wd1, Wd1_bf, 1, (long long)4 * H_ * 2 * H_, 1);
    cvt(stream, Wd2, Wd2p_bf, V_, (long long)4 * H_, NPAD_);

    // 6) attentions
    mgemm(stream, 0, 0, 0, h_top_bf, Wansq_bf, bansq, nullptr, proj, H_, BT_, H_, H_);
    attend_kernel<<<dim3(BT_), dim3(256), 0, stream>>>(q_emb_bf, LQ_, proj, waq, baq, fcat_bf, 0);
    mgemm(stream, 0, 0, 0, h_top_bf, Wansh_bf, bansh, nullptr, proj, H_, BT_, H_, H_);
    attend_kernel<<<dim3(BT_), dim3(256), 0, stream>>>(h_emb_bf, LH_, proj, wah, bah, fcat_bf, 512);
    mgemm(stream, 0, 0, 0, h_top_bf, Wansi_bf, bansi, nullptr, proj, H_, BT_, H_, H_);
    attend_kernel<<<dim3(BT_), dim3(256), 0, stream>>>(i_emb_bf, LI_, proj, wai, bai, fcat_bf, 1024);

    // 7) fusion = [h_top, tanh(fcat @ Wcat^T + bcat)]
    copy_fusion_left<<<dim3(BT_ * H_ / 8 / 256), dim3(256), 0, stream>>>(h_top_bf, fusion_bf);
    mgemm(stream, 1, 1, 0, fcat_bf, Wcat_bf, bcat, nullptr, fusion_bf + H_, 2 * H_, BT_, H_, 3 * H_);

    // 8) decoder
    mgemm(stream, 2, 1, 0, fusion_bf, Wd1_bf, bd1, nullptr, dec1_bf, 4 * H_, BT_, 4 * H_, 2 * H_);
    mgemm(stream, 0, 0, 0, dec1_bf, Wd2p_bf, bd2, nullptr, out, V_, BT_, V_, 4 * H_);

    // 9) in-place log_softmax(BETA * dec)
    log_softmax_kernel<<<dim3(BT_), dim3(256), 0, stream>>>(out);

    // 10) tail: hT, cT (st_h/st_c contiguous)
    hipMemcpyAsync(out + (long long)BT_ * V_, st_h,
                   4LL * BH_ * sizeof(float), hipMemcpyDeviceToDevice, stream);
}

// Round 6
// 1641.242 us; speedup vs baseline: 1.2053x; 1.2053x over previous
//
#include <hip/hip_runtime.h>
#include <cmath>

#define B_ 256
#define T_ 20
#define H_ 512
#define V_ 8964
#define LQ_ 40
#define LH_ 80
#define LI_ 49
#define BT_ (B_ * T_)   // 5120
#define BH_ (B_ * H_)   // 131072
#define NPAD_ 9088      // V_ padded to multiple of 128
#define BETA_ 3.0f

typedef __attribute__((ext_vector_type(8))) short bf16x8;
typedef __attribute__((ext_vector_type(4))) float f32x4;
typedef __attribute__((ext_vector_type(8))) unsigned short u16x8;

static __device__ __forceinline__ unsigned short f2bf(float f) {
    union { float f; unsigned u; } v; v.f = f;
    unsigned r = v.u + 0x7FFF + ((v.u >> 16) & 1);
    return (unsigned short)(r >> 16);
}
static __device__ __forceinline__ float bf2f(unsigned short u) {
    union { unsigned u; float f; } v; v.u = ((unsigned)u) << 16;
    return v.f;
}

// ---------------------------------------------------------------------------
// f32 -> bf16 convert with optional row padding (rows >= srcRows get zeros).
// ---------------------------------------------------------------------------
__global__ __launch_bounds__(256) void cvt_kernel(
    const float* __restrict__ src, unsigned short* __restrict__ dst,
    long long srcRows, long long cols, long long dstRows)
{
    const long long total = dstRows * cols;
    const long long e0 = ((long long)blockIdx.x * 256 + threadIdx.x) * 8;
    if (e0 >= total) return;
    const long long row = e0 / cols;
    u16x8 v;
    if (row < srcRows) {
        float4 a = *reinterpret_cast<const float4*>(src + e0);
        float4 b = *reinterpret_cast<const float4*>(src + e0 + 4);
        v[0] = f2bf(a.x); v[1] = f2bf(a.y); v[2] = f2bf(a.z); v[3] = f2bf(a.w);
        v[4] = f2bf(b.x); v[5] = f2bf(b.y); v[6] = f2bf(b.z); v[7] = f2bf(b.w);
    } else {
        v = (u16x8)0;
    }
    *reinterpret_cast<u16x8*>(dst + e0) = v;
}

static void cvt(hipStream_t s, const float* src, unsigned short* dst,
                long long srcRows, long long cols, long long dstRows)
{
    long long total = dstRows * cols;
    cvt_kernel<<<dim3((unsigned)((total / 8 + 255) / 256)), dim3(256), 0, s>>>(
        src, dst, srcRows, cols, dstRows);
}

// ---------------------------------------------------------------------------
// Fused multi-segment f32->bf16 weight convert (one launch for 8 weights).
// Each block handles 2048 contiguous elements; all segment sizes are
// multiples of 2048 so segment choice is block-uniform.
// Segment element counts: Wq/Wh/Wi = H*2H = 524288; Wansq/h/i = H*H = 262144;
// Wcat = H*3H = 786432; Wd1 = 4H*2H = 2097152.  Total 5,242,880 -> 2560 blocks.
// ---------------------------------------------------------------------------
struct WcvtArgs { const float* src[8]; unsigned short* dst[8]; };

__global__ __launch_bounds__(256) void wcvt_kernel(WcvtArgs a)
{
    static constexpr long long SZ[8] = {524288, 524288, 524288, 262144,
                                        262144, 262144, 786432, 2097152};
    long long off = (long long)blockIdx.x * 2048;
    int seg = 0;
#pragma unroll
    for (int i = 0; i < 8; ++i)
        if (seg == i && off >= SZ[i]) { off -= SZ[i]; ++seg; }
    const float* src = a.src[seg];
    unsigned short* dst = a.dst[seg];
    const long long e = off + (long long)threadIdx.x * 8;
    float4 x = *reinterpret_cast<const float4*>(src + e);
    float4 y = *reinterpret_cast<const float4*>(src + e + 4);
    u16x8 v;
    v[0] = f2bf(x.x); v[1] = f2bf(x.y); v[2] = f2bf(x.z); v[3] = f2bf(x.w);
    v[4] = f2bf(y.x); v[5] = f2bf(y.y); v[6] = f2bf(y.z); v[7] = f2bf(y.w);
    *reinterpret_cast<u16x8*>(dst + e) = v;
}

// ---------------------------------------------------------------------------
// Gate-permuting convert for LSTM weights [2048][512] -> bf16:
// dst row n' = (h>>4)*64 + g*16 + (h&15)  <-  src row g*512+h.
// ---------------------------------------------------------------------------
__global__ __launch_bounds__(256) void cvt_perm_kernel(
    const float* __restrict__ src, unsigned short* __restrict__ dst)
{
    const long long e0 = ((long long)blockIdx.x * 256 + threadIdx.x) * 8;
    if (e0 >= 2048LL * 512) return;
    const int drow = (int)(e0 >> 9);
    const int col = (int)(e0 & 511);
    const int g = (drow >> 4) & 3;
    const int hsrc = ((drow >> 6) << 4) | (drow & 15);
    const int srow = (g << 9) | hsrc;
    const float* sp = src + (long long)srow * 512 + col;
    float4 a = *reinterpret_cast<const float4*>(sp);
    float4 b = *reinterpret_cast<const float4*>(sp + 4);
    u16x8 v;
    v[0] = f2bf(a.x); v[1] = f2bf(a.y); v[2] = f2bf(a.z); v[3] = f2bf(a.w);
    v[4] = f2bf(b.x); v[5] = f2bf(b.y); v[6] = f2bf(b.z); v[7] = f2bf(b.w);
    *reinterpret_cast<u16x8*>(dst + e0) = v;
}

// dst[n'] = b1[orig(n')] + b2[orig(n')], n' in [0,2048)
__global__ __launch_bounds__(256) void bias_perm_kernel(
    const float* __restrict__ b1, const float* __restrict__ b2,
    float* __restrict__ dst)
{
    const int n = blockIdx.x * 256 + threadIdx.x;
    if (n < 2048) {
        const int g = (n >> 4) & 3;
        const int h = ((n >> 6) << 4) | (n & 15);
        const int orig = (g << 9) | h;
        dst[n] = b1[orig] + b2[orig];
    }
}

// ---------------------------------------------------------------------------
// A-fragment loader: 8 contiguous elements at element-index idx.
// ---------------------------------------------------------------------------
template <int AF32>
static __device__ __forceinline__ int4 ldA8(const void* A, long long idx)
{
    if constexpr (AF32) {
        const float* p = (const float*)A + idx;
        float4 a = *reinterpret_cast<const float4*>(p);
        float4 b = *reinterpret_cast<const float4*>(p + 4);
        union { int4 i4; unsigned short u[8]; } r;
        r.u[0] = f2bf(a.x); r.u[1] = f2bf(a.y); r.u[2] = f2bf(a.z); r.u[3] = f2bf(a.w);
        r.u[4] = f2bf(b.x); r.u[5] = f2bf(b.y); r.u[6] = f2bf(b.z); r.u[7] = f2bf(b.w);
        return r.i4;
    } else {
        return *reinterpret_cast<const int4*>((const unsigned short*)A + idx);
    }
}

// ---------------------------------------------------------------------------
// bf16 MFMA GEMM: C[m,n] = act(A[m,:]·W[n,:] + bias1[n] + bias2[n])
// 128x128 tile, BK=32, 4 waves. Bijective XCD swizzle + m-fastest tile order.
// ---------------------------------------------------------------------------
template <int ACT, int OUTBF, int AF32>
__global__ __launch_bounds__(256, 2) void mfma_gemm(
    const void* __restrict__ A, const unsigned short* __restrict__ W,
    const float* __restrict__ bias1, const float* __restrict__ bias2,
    void* __restrict__ C, long long ldc, int Nreal, int K)
{
    __shared__ __align__(16) unsigned short As[128][32];
    __shared__ __align__(16) unsigned short Bs[128][32];
    const int tid = threadIdx.x;
    const int lane = tid & 63;
    const int wave = tid >> 6;
    const int wm = wave >> 1, wn = wave & 1;

    const int nwg = gridDim.x * gridDim.y;
    const int orig = blockIdx.y * gridDim.x + blockIdx.x;
    const int xcd = orig & 7, base = orig >> 3;
    const int q8 = nwg >> 3, r8 = nwg & 7;
    const int wg = (xcd < r8 ? xcd * (q8 + 1) : r8 * (q8 + 1) + (xcd - r8) * q8) + base;
    const int m0 = (wg % gridDim.y) * 128;
    const int n0 = (wg / gridDim.y) * 128;

    const int r = tid >> 2;
    const int ck = (tid & 3) * 8;

    const unsigned short* Wp = W + (long long)n0 * K;

    f32x4 acc[4][4] = {};

    int4 ra0, ra1, rb0, rb1;
    ra0 = ldA8<AF32>(A, (long long)(m0 + r) * K + ck);
    ra1 = ldA8<AF32>(A, (long long)(m0 + r + 64) * K + ck);
    rb0 = *reinterpret_cast<const int4*>(Wp + (long long)r * K + ck);
    rb1 = *reinterpret_cast<const int4*>(Wp + (long long)(r + 64) * K + ck);

    for (int k0 = 0; k0 < K; k0 += 32) {
        __syncthreads();
        *reinterpret_cast<int4*>(&As[r][ck]) = ra0;
        *reinterpret_cast<int4*>(&As[r + 64][ck]) = ra1;
        *reinterpret_cast<int4*>(&Bs[r][ck]) = rb0;
        *reinterpret_cast<int4*>(&Bs[r + 64][ck]) = rb1;
        __syncthreads();
        if (k0 + 32 < K) {
            const int kn = k0 + 32 + ck;
            ra0 = ldA8<AF32>(A, (long long)(m0 + r) * K + kn);
            ra1 = ldA8<AF32>(A, (long long)(m0 + r + 64) * K + kn);
            rb0 = *reinterpret_cast<const int4*>(Wp + (long long)r * K + kn);
            rb1 = *reinterpret_cast<const int4*>(Wp + (long long)(r + 64) * K + kn);
        }
        const int lr = lane & 15, lk = (lane >> 4) * 8;
        bf16x8 af[4], bfr[4];
#pragma unroll
        for (int i = 0; i < 4; ++i) {
            af[i]  = *reinterpret_cast<const bf16x8*>(&As[wm * 64 + i * 16 + lr][lk]);
            bfr[i] = *reinterpret_cast<const bf16x8*>(&Bs[wn * 64 + i * 16 + lr][lk]);
        }
#pragma unroll
        for (int i = 0; i < 4; ++i)
#pragma unroll
            for (int j = 0; j < 4; ++j)
                acc[i][j] = __builtin_amdgcn_mfma_f32_16x16x32_bf16(
                    af[i], bfr[j], acc[i][j], 0, 0, 0);
    }

    const int lr = lane & 15, lrow4 = (lane >> 4) * 4;
#pragma unroll
    for (int j = 0; j < 4; ++j) {
        const int col = n0 + wn * 64 + j * 16 + lr;
        if (col >= Nreal) continue;
        float bsum = 0.f;
        if (bias1) bsum += bias1[col];
        if (bias2) bsum += bias2[col];
#pragma unroll
        for (int i = 0; i < 4; ++i) {
#pragma unroll
            for (int rr = 0; rr < 4; ++rr) {
                const int row = m0 + wm * 64 + i * 16 + lrow4 + rr;
                float v = acc[i][j][rr] + bsum;
                if (ACT == 1) v = tanhf(v);
                if (ACT == 2) v = fmaxf(v, 0.f);
                if (OUTBF)
                    ((unsigned short*)C)[(long long)row * ldc + col] = f2bf(v);
                else
                    ((float*)C)[(long long)row * ldc + col] = v;
            }
        }
    }
}

static void mgemm(hipStream_t s, int act, int outbf, int af32,
                  const void* A, const unsigned short* W,
                  const float* b1, const float* b2,
                  void* C, long long ldc, int M, int Nreal, int K)
{
    dim3 grid((Nreal + 127) / 128, M / 128), blk(256);
#define MG(a, o, f) mfma_gemm<a, o, f><<<grid, blk, 0, s>>>(A, W, b1, b2, C, ldc, Nreal, K)
    if (af32) {
        if (outbf) { if (act == 1) MG(1,1,1); else if (act == 2) MG(2,1,1); else MG(0,1,1); }
        else       { if (act == 1) MG(1,0,1); else if (act == 2) MG(2,0,1); else MG(0,0,1); }
    } else {
        if (outbf) { if (act == 1) MG(1,1,0); else if (act == 2) MG(2,1,0); else MG(0,1,0); }
        else       { if (act == 1) MG(1,0,0); else if (act == 2) MG(2,0,0); else MG(0,0,0); }
    }
#undef MG
}

// ---------------------------------------------------------------------------
// Persistent fused LSTM, v2. ONE launch, 128 blocks x 256 threads (1 block/CU,
// 128 KB LDS). Blocks 0..63: layer 0 step s; 64..127: layer 1 step s-1.
// Block = 128 rows (M-tile) x 64 gate-cols (one h-group of 16 h x 4 gates,
// permutation n' = (h>>4)*64 + g*16 + (h&15)). 4 waves of 32 rows x 64 cols.
// Weights stay in LDS (XOR-swizzled) for all steps; A goes global->register
// with a 4-deep prefetch ring; NO __syncthreads inside the K-loop; c-state
// lives in registers for the entire recurrence. Grid barrier between steps.
// ---------------------------------------------------------------------------
__global__ __launch_bounds__(256, 1) void lstm_persistent_kernel(
    const unsigned short* __restrict__ emb_bf,    // [b*T+t][512]
    const unsigned short* __restrict__ Wih0p, const unsigned short* __restrict__ Whh0p,
    const unsigned short* __restrict__ Wih1p, const unsigned short* __restrict__ Whh1p,
    const float* __restrict__ bp0, const float* __restrict__ bp1,
    const float* __restrict__ c0,                 // [2][B][512]
    unsigned short* __restrict__ hbuf,            // [4][B][512] bf16
    float* __restrict__ st_h,                     // [2][B][512]
    float* __restrict__ st_c,                     // [2][B][512]
    unsigned short* __restrict__ h_top,           // [b*T+t][512] bf16
    int* bar)
{
    __shared__ __align__(16) unsigned short Wlds[2][64][512];   // 128 KB

    const int gid = blockIdx.x;          // 0..127
    const int grp = gid >> 6;
    const int id  = gid & 63;
    const int mt = id >> 5, nt = id & 31;
    const int m0 = mt * 128, n0 = nt * 64;
    const int tid = threadIdx.x;
    const int lane = tid & 63;
    const int w = tid >> 6;              // wave: rows w*32 .. w*32+31
    const int lr = lane & 15;
    const int hi = lane >> 4;            // 0..3
    const int hi4 = hi * 4;

    const unsigned short* W1g = (grp ? Wih1p : Wih0p) + (long long)n0 * H_;
    const unsigned short* W2g = (grp ? Whh1p : Whh0p) + (long long)n0 * H_;

    // ---- stage weight slices into LDS (XOR swizzle: byte_in_row ^= (row&7)<<4)
#pragma unroll
    for (int it = 0; it < 16; ++it) {
        const int e = (tid + it * 256) * 8;      // 0..32760
        const int row = e >> 9, col = e & 511;
        const int bir = (col * 2) ^ ((row & 7) << 4);
        char* dst = (char*)Wlds + row * 1024 + bir;
        *reinterpret_cast<int4*>(dst) =
            *reinterpret_cast<const int4*>(W1g + (long long)row * H_ + col);
        *reinterpret_cast<int4*>(dst + 65536) =
            *reinterpret_cast<const int4*>(W2g + (long long)row * H_ + col);
    }
    __syncthreads();

    // ---- per-lane constants
    const int h = n0 / 4 + lr;                   // global h = nt*16 + lr
    const float* bp = grp ? bp1 : bp0;
    float bg[4];
#pragma unroll
    for (int g = 0; g < 4; ++g) bg[g] = bp[n0 + g * 16 + lr];

    const int ar0 = m0 + w * 32 + lr;            // A rows for frag i=0,1
    const int ar1 = ar0 + 16;

    // c-state in registers
    float creg[2][4];
#pragma unroll
    for (int i = 0; i < 2; ++i)
#pragma unroll
        for (int rr = 0; rr < 4; ++rr) {
            const int b = m0 + w * 32 + i * 16 + hi4 + rr;
            creg[i][rr] = c0[(long long)grp * BH_ + (long long)b * H_ + h];
        }

    // LDS read bases per j (byte), XOR-swizzle folded in:
    // addr = (j*16+lr)*1024 + (hi*16 ^ ((lr&3)<<4)) + ((kk ^ ((lr>>2)&1))<<6) + p*65536
    int bbase[4];
#pragma unroll
    for (int j = 0; j < 4; ++j)
        bbase[j] = (j * 16 + lr) * 1024 + ((hi * 16) ^ ((lr & 3) << 4));
    const int xk6 = ((lr >> 2) & 1) << 6;

    for (int s = 0; s <= T_; ++s) {
        const bool active = (grp == 0) ? (s < T_) : (s >= 1);
        if (active) {
            const int t = grp ? (s - 1) : s;
            const int pr = s & 1;
            const unsigned short *A1, *A2;
            long long sA1;
            unsigned short* hout;
            if (grp == 0) {
                A1 = emb_bf + (long long)t * H_; sA1 = (long long)T_ * H_;
                A2 = hbuf + (long long)pr * BH_;
                hout = hbuf + (long long)(pr ^ 1) * BH_;
            } else {
                A1 = hbuf + (long long)pr * BH_; sA1 = H_;
                A2 = hbuf + (long long)(2 + pr) * BH_;
                hout = hbuf + (long long)(2 + (pr ^ 1)) * BH_;
            }
            const unsigned short* pA[2][2] = {
                { A1 + (long long)ar0 * sA1 + hi * 8, A1 + (long long)ar1 * sA1 + hi * 8 },
                { A2 + (long long)ar0 * H_  + hi * 8, A2 + (long long)ar1 * H_  + hi * 8 } };

            f32x4 acc[2][4] = {};
            int4 abuf[4][2];
#pragma unroll
            for (int pf = 0; pf < 4; ++pf) {
                abuf[pf][0] = *reinterpret_cast<const int4*>(pA[0][0] + pf * 32);
                abuf[pf][1] = *reinterpret_cast<const int4*>(pA[0][1] + pf * 32);
            }
#pragma unroll
            for (int it = 0; it < 32; ++it) {
                const int p = it >> 4, kk = it & 15;
                int4 ca = abuf[it & 3][0];
                int4 cb = abuf[it & 3][1];
                if (it + 4 < 32) {
                    const int np = (it + 4) >> 4, nk = (it + 4) & 15;
                    abuf[it & 3][0] = *reinterpret_cast<const int4*>(pA[np][0] + nk * 32);
                    abuf[it & 3][1] = *reinterpret_cast<const int4*>(pA[np][1] + nk * 32);
                }
                const bf16x8 a0 = *reinterpret_cast<const bf16x8*>(&ca);
                const bf16x8 a1 = *reinterpret_cast<const bf16x8*>(&cb);
                const int kb = ((kk << 6) ^ xk6) + (p << 16);
#pragma unroll
                for (int j = 0; j < 4; ++j) {
                    const bf16x8 bf = *reinterpret_cast<const bf16x8*>(
                        (const char*)Wlds + bbase[j] + kb);
                    acc[0][j] = __builtin_amdgcn_mfma_f32_16x16x32_bf16(a0, bf, acc[0][j], 0, 0, 0);
                    acc[1][j] = __builtin_amdgcn_mfma_f32_16x16x32_bf16(a1, bf, acc[1][j], 0, 0, 0);
                }
            }

            // register cell (gate g = j; D row = hi4+rr, col = lr)
#pragma unroll
            for (int i = 0; i < 2; ++i) {
#pragma unroll
                for (int rr = 0; rr < 4; ++rr) {
                    const int b = m0 + w * 32 + i * 16 + hi4 + rr;
                    const float gi = acc[i][0][rr] + bg[0];
                    const float gf = acc[i][1][rr] + bg[1];
                    const float gg = acc[i][2][rr] + bg[2];
                    const float go = acc[i][3][rr] + bg[3];
                    const float i_ = 1.f / (1.f + expf(-gi));
                    const float f_ = 1.f / (1.f + expf(-gf));
                    const float o_ = 1.f / (1.f + expf(-go));
                    const float cn = f_ * creg[i][rr] + i_ * tanhf(gg);
                    const float hn = o_ * tanhf(cn);
                    creg[i][rr] = cn;
                    const long long cidx = (long long)b * H_ + h;
                    hout[cidx] = f2bf(hn);
                    if (grp == 1) h_top[((long long)b * T_ + t) * H_ + h] = f2bf(hn);
                    if (t == T_ - 1) {
                        st_h[(long long)grp * BH_ + cidx] = hn;
                        st_c[(long long)grp * BH_ + cidx] = cn;
                    }
                }
            }
        }
        if (s < T_) {
            __syncthreads();
            if (tid == 0) {
                __hip_atomic_fetch_add(bar, 1, __ATOMIC_RELEASE, __HIP_MEMORY_SCOPE_AGENT);
                const int tgt = 128 * (s + 1);
                while (__hip_atomic_load(bar, __ATOMIC_ACQUIRE, __HIP_MEMORY_SCOPE_AGENT) < tgt)
                    __builtin_amdgcn_s_sleep(2);
                __threadfence();
            }
            __syncthreads();
        }
    }
}

// ---------------------------------------------------------------------------
// Fused attention over bf16 ctx: logits -> softmax -> weighted sum (bf16 out).
// ---------------------------------------------------------------------------
__global__ __launch_bounds__(256) void attend_kernel(
    const unsigned short* __restrict__ ctx, int Lx,
    const float* __restrict__ proj,
    const float* __restrict__ wa, const float* __restrict__ ba,
    unsigned short* __restrict__ fcat, int off)
{
    __shared__ float p_lds[512];
    __shared__ float wa_lds[512];
    __shared__ float lg[96];
    const int bt = blockIdx.x;
    const int b = bt / T_;
    const int tid = threadIdx.x;

    p_lds[tid] = proj[(long long)bt * H_ + tid];
    p_lds[tid + 256] = proj[(long long)bt * H_ + tid + 256];
    wa_lds[tid] = wa[tid];
    wa_lds[tid + 256] = wa[tid + 256];
    __syncthreads();

    const int wid = tid >> 6, lane = tid & 63;
    const float bav = ba[0];
    for (int l = wid; l < Lx; l += 4) {
        const unsigned short* crow = ctx + ((long long)b * Lx + l) * H_;
        float acc = 0.f;
#pragma unroll
        for (int j = 0; j < 8; ++j) {
            const int hp = lane + 64 * j;
            acc += wa_lds[hp] * tanhf(bf2f(crow[hp]) + p_lds[hp]);
        }
        for (int o = 32; o > 0; o >>= 1) acc += __shfl_down(acc, o);
        if (lane == 0) lg[l] = acc + bav;
    }
    __syncthreads();
    if (tid == 0) {
        float m = -1e30f;
        for (int l = 0; l < Lx; ++l) m = fmaxf(m, lg[l]);
        float ssum = 0.f;
        for (int l = 0; l < Lx; ++l) { const float e = expf(lg[l] - m); lg[l] = e; ssum += e; }
        const float inv = 1.f / ssum;
        for (int l = 0; l < Lx; ++l) lg[l] *= inv;
    }
    __syncthreads();
    for (int hp = tid; hp < H_; hp += 256) {
        float acc = 0.f;
        for (int l = 0; l < Lx; ++l)
            acc += lg[l] * bf2f(ctx[((long long)b * Lx + l) * H_ + hp]);
        fcat[(long long)bt * (3 * H_) + off + hp] = f2bf(acc);
    }
}

// fusion_bf[:, 0:512] = h_top_bf
__global__ __launch_bounds__(256) void copy_fusion_left(
    const unsigned short* __restrict__ h_top, unsigned short* __restrict__ fusion)
{
    const long long e0 = ((long long)blockIdx.x * 256 + threadIdx.x) * 8;  // < BT*H
    const long long rr = e0 >> 9, cpos = e0 & 511;
    *reinterpret_cast<u16x8*>(&fusion[rr * 1024 + cpos]) =
        *reinterpret_cast<const u16x8*>(&h_top[e0]);
}

// In-place log_softmax(BETA * x) per row of V_; row cached in registers
// (single global read + single write).
__global__ __launch_bounds__(256) void log_softmax_kernel(float* __restrict__ out)
{
    __shared__ float red[4];
    __shared__ float bc;
    const long long base = (long long)blockIdx.x * V_;
    const int tid = threadIdx.x, lane = tid & 63, wid = tid >> 6;

    float r[36];
    float m = -1e30f;
#pragma unroll
    for (int i = 0; i < 36; ++i) {
        const int v = tid + i * 256;
        r[i] = (v < V_) ? BETA_ * out[base + v] : -1e30f;
        m = fmaxf(m, r[i]);
    }
    for (int o = 32; o > 0; o >>= 1) m = fmaxf(m, __shfl_down(m, o));
    if (lane == 0) red[wid] = m;
    __syncthreads();
    if (tid == 0)
        bc = fmaxf(fmaxf(red[0], red[1]), fmaxf(red[2], red[3]));
    __syncthreads();
    m = bc;

    float s = 0.f;
#pragma unroll
    for (int i = 0; i < 36; ++i) s += expf(r[i] - m);
    for (int o = 32; o > 0; o >>= 1) s += __shfl_down(s, o);
    if (lane == 0) red[wid] = s;
    __syncthreads();
    if (tid == 0) bc = m + logf(red[0] + red[1] + red[2] + red[3]);
    __syncthreads();
    const float ls = bc;
#pragma unroll
    for (int i = 0; i < 36; ++i) {
        const int v = tid + i * 256;
        if (v < V_) out[base + v] = r[i] - ls;
    }
}

// ---------------------------------------------------------------------------
extern "C" void kernel_launch(void* const* d_in, const int* in_sizes, int n_in,
                              void* d_out_, int out_size, void* d_ws, size_t ws_size,
                              hipStream_t stream)
{
    const float* emb      = (const float*)d_in[0];
    const float* question = (const float*)d_in[1];
    const float* history  = (const float*)d_in[2];
    const float* image    = (const float*)d_in[3];
    const float* h0       = (const float*)d_in[4];
    const float* c0       = (const float*)d_in[5];
    const float* Wih      = (const float*)d_in[6];
    const float* Whh      = (const float*)d_in[7];
    const float* bih      = (const float*)d_in[8];
    const float* bhh      = (const float*)d_in[9];
    const float* Wq    = (const float*)d_in[10]; const float* bq    = (const float*)d_in[11];
    const float* Wansq = (const float*)d_in[12]; const float* bansq = (const float*)d_in[13];
    const float* waq   = (const float*)d_in[14]; const float* baq   = (const float*)d_in[15];
    const float* Wh    = (const float*)d_in[16]; const float* bh    = (const float*)d_in[17];
    const float* Wansh = (const float*)d_in[18]; const float* bansh = (const float*)d_in[19];
    const float* wah   = (const float*)d_in[20]; const float* bah   = (const float*)d_in[21];
    const float* Wi    = (const float*)d_in[22]; const float* bi    = (const float*)d_in[23];
    const float* Wansi = (const float*)d_in[24]; const float* bansi = (const float*)d_in[25];
    const float* wai   = (const float*)d_in[26]; const float* bai   = (const float*)d_in[27];
    const float* Wcat  = (const float*)d_in[28]; const float* bcat  = (const float*)d_in[29];
    const float* Wd1   = (const float*)d_in[30]; const float* bd1   = (const float*)d_in[31];
    const float* Wd2   = (const float*)d_in[32]; const float* bd2   = (const float*)d_in[33];

    float* out = (float*)d_out_;

    // ---- workspace layout ----
    int*   bar  = (int*)d_ws;                          // barrier counter
    float* st_h = (float*)((char*)d_ws + 256);         // 2*BH fp32 (st_c follows)
    float* st_c = st_h + 2LL * BH_;                    // 2*BH fp32
    float* bp0  = st_c + 2LL * BH_;                    // 2048
    float* bp1  = bp0 + 2048;                          // 2048
    unsigned short* hbuf   = (unsigned short*)(bp1 + 2048);     // 4*BH bf16
    unsigned short* Wih0p  = hbuf + 4LL * BH_;                  // 2048*512 each
    unsigned short* Whh0p  = Wih0p + 2048LL * H_;
    unsigned short* Wih1p  = Whh0p + 2048LL * H_;
    unsigned short* Whh1p  = Wih1p + 2048LL * H_;
    unsigned short* emb_bf = Whh1p + 2048LL * H_;               // BT*H
    unsigned short* h_top_bf = emb_bf + (long long)BT_ * H_;    // BT*H
    unsigned short* q_emb_bf = h_top_bf + (long long)BT_ * H_;  // B*LQ*H
    unsigned short* h_emb_bf = q_emb_bf + (long long)B_ * LQ_ * H_;
    unsigned short* i_emb_bf = h_emb_bf + (long long)B_ * LH_ * H_;
    unsigned short* dec1_bf  = i_emb_bf + (long long)B_ * LI_ * H_;  // BT*4H
    unsigned short* Wd2p_bf  = dec1_bf + (long long)BT_ * 4 * H_;    // NPAD*4H

    // ---- scratch inside d_out ----
    unsigned short* Wq_bf = (unsigned short*)out;
    unsigned short* Wh_bf = Wq_bf + (long long)H_ * 2 * H_;
    unsigned short* Wi_bf = Wh_bf + (long long)H_ * 2 * H_;
    float* proj = out;                                              // BT*H fp32
    unsigned short* fcat_bf   = (unsigned short*)(proj + (long long)BT_ * H_); // BT*3H
    unsigned short* fusion_bf = fcat_bf + (long long)BT_ * 3 * H_;  // BT*2H
    unsigned short* Wansq_bf  = fusion_bf + (long long)BT_ * 2 * H_;
    unsigned short* Wansh_bf  = Wansq_bf + (long long)H_ * H_;
    unsigned short* Wansi_bf  = Wansh_bf + (long long)H_ * H_;
    unsigned short* Wcat_bf   = Wansi_bf + (long long)H_ * H_;      // H*3H
    unsigned short* Wd1_bf    = Wcat_bf + (long long)H_ * 3 * H_;   // 4H*2H

    // 1) all plain weight converts in ONE launch (2560 blocks = 5,242,880 elems)
    {
        WcvtArgs a;
        a.src[0] = Wq;    a.dst[0] = Wq_bf;
        a.src[1] = Wh;    a.dst[1] = Wh_bf;
        a.src[2] = Wi;    a.dst[2] = Wi_bf;
        a.src[3] = Wansq; a.dst[3] = Wansq_bf;
        a.src[4] = Wansh; a.dst[4] = Wansh_bf;
        a.src[5] = Wansi; a.dst[5] = Wansi_bf;
        a.src[6] = Wcat;  a.dst[6] = Wcat_bf;
        a.src[7] = Wd1;   a.dst[7] = Wd1_bf;
        wcvt_kernel<<<dim3(2560), dim3(256), 0, stream>>>(a);
    }
    cvt(stream, Wd2, Wd2p_bf, V_, (long long)4 * H_, NPAD_);

    // 2) LSTM prep: emb, gate-permuted weights/biases, h init, barrier=0
    cvt(stream, emb, emb_bf, 1, (long long)BT_ * H_, 1);
    cvt_perm_kernel<<<dim3(512), dim3(256), 0, stream>>>(Wih, Wih0p);
    cvt_perm_kernel<<<dim3(512), dim3(256), 0, stream>>>(Whh, Whh0p);
    cvt_perm_kernel<<<dim3(512), dim3(256), 0, stream>>>(Wih + 2048LL * H_, Wih1p);
    cvt_perm_kernel<<<dim3(512), dim3(256), 0, stream>>>(Whh + 2048LL * H_, Whh1p);
    bias_perm_kernel<<<dim3(8), dim3(256), 0, stream>>>(bih, bhh, bp0);
    bias_perm_kernel<<<dim3(8), dim3(256), 0, stream>>>(bih + 2048, bhh + 2048, bp1);
    cvt(stream, h0, hbuf, 1, BH_, 1);                   // layer0 init -> slot 0
    cvt(stream, h0 + BH_, hbuf + 3LL * BH_, 1, BH_, 1); // layer1 init -> slot 3
    hipMemsetAsync(bar, 0, 256, stream);

    // 3) context projections (fp32 A converted in-GEMM)
    mgemm(stream, 0, 1, 1, question, Wq_bf, bq, nullptr, q_emb_bf, H_, B_ * LQ_, H_, 2 * H_);
    mgemm(stream, 0, 1, 1, history,  Wh_bf, bh, nullptr, h_emb_bf, H_, B_ * LH_, H_, 2 * H_);
    mgemm(stream, 0, 1, 1, image,    Wi_bf, bi, nullptr, i_emb_bf, H_, B_ * LI_, H_, 2 * H_);

    // 4) persistent fused LSTM (one launch, weights-in-LDS, c-in-registers)
    lstm_persistent_kernel<<<dim3(128), dim3(256), 0, stream>>>(
        emb_bf, Wih0p, Whh0p, Wih1p, Whh1p, bp0, bp1, c0,
        hbuf, st_h, st_c, h_top_bf, bar);

    // 5) attentions
    mgemm(stream, 0, 0, 0, h_top_bf, Wansq_bf, bansq, nullptr, proj, H_, BT_, H_, H_);
    attend_kernel<<<dim3(BT_), dim3(256), 0, stream>>>(q_emb_bf, LQ_, proj, waq, baq, fcat_bf, 0);
    mgemm(stream, 0, 0, 0, h_top_bf, Wansh_bf, bansh, nullptr, proj, H_, BT_, H_, H_);
    attend_kernel<<<dim3(BT_), dim3(256), 0, stream>>>(h_emb_bf, LH_, proj, wah, bah, fcat_bf, 512);
    mgemm(stream, 0, 0, 0, h_top_bf, Wansi_bf, bansi, nullptr, proj, H_, BT_, H_, H_);
    attend_kernel<<<dim3(BT_), dim3(256), 0, stream>>>(i_emb_bf, LI_, proj, wai, bai, fcat_bf, 1024);

    // 6) fusion = [h_top, tanh(fcat @ Wcat^T + bcat)]
    copy_fusion_left<<<dim3(BT_ * H_ / 8 / 256), dim3(256), 0, stream>>>(h_top_bf, fusion_bf);
    mgemm(stream, 1, 1, 0, fcat_bf, Wcat_bf, bcat, nullptr, fusion_bf + H_, 2 * H_, BT_, H_, 3 * H_);

    // 7) decoder
    mgemm(stream, 2, 1, 0, fusion_bf, Wd1_bf, bd1, nullptr, dec1_bf, 4 * H_, BT_, 4 * H_, 2 * H_);
    mgemm(stream, 0, 0, 0, dec1_bf, Wd2p_bf, bd2, nullptr, out, V_, BT_, V_, 4 * H_);

    // 8) in-place log_softmax(BETA * dec), register-cached single pass
    log_softmax_kernel<<<dim3(BT_), dim3(256), 0, stream>>>(out);

    // 9) tail: hT, cT (st_h/st_c contiguous)
    hipMemcpyAsync(out + (long long)BT_ * V_, st_h,
                   4LL * BH_ * sizeof(float), hipMemcpyDeviceToDevice, stream);
}